// Round 18
// baseline (32.672 us; speedup 1.0000x reference)
//
#include <hip/hip_runtime.h>

// Problem constants (fixed by the reference file): B=8, N=4096.
#define NN 4096
#define BB 8
#define JT 4   // ISNet rows (j) per block

typedef float v2f __attribute__((ext_vector_type(2)));
typedef float v4f __attribute__((ext_vector_type(4)));

// R14 structure byte-for-byte (best clean: 23.8 µs) + ONE register-free
// change: all w (ISNet) loads are NON-TEMPORAL (nt -> bypass L1). w has no
// reuse within a wave but is 2/3 of the byte stream; I rows (shared by the
// CU's resident blocks) are the only reusable data. Freeing L1 for I tests
// whether L1 contention is the invariant ~24 µs wall.
// R17 fix: __builtin_nontemporal_load needs clang ext-vector pointers, not
// HIP_vector_type -- w/I pointers are now v4f*.

__global__ __launch_bounds__(256, 4) void epi_kernel(
    const float* __restrict__ state,    // [B,4,N]
    const float* __restrict__ ISNet,    // [N,N]
    const float* __restrict__ psMatrix, // [4,4]
    const float* __restrict__ U,        // [N]
    float* __restrict__ out)            // [B,4,N]
{
    const int j0   = blockIdx.x * JT;
    const int tid  = threadIdx.x;
    const int wave = tid >> 6;
    const int lane = tid & 63;
    const int b0   = wave * 2;          // this wave's two batches

    const float p01 = psMatrix[1];      // psM[0,1] == psMatrix[0,1]

    float  cf[JT][2];
    float  qp[JT][2];                   // pending q4 from the even stage
    double prod[JT][2];
    #pragma unroll
    for (int jj = 0; jj < JT; ++jj) {
        #pragma unroll
        for (int bi = 0; bi < 2; ++bi) {
            cf[jj][bi]   = state[(size_t)(b0 + bi) * 4 * NN + (j0 + jj)] * p01;
            prod[jj][bi] = 1.0;
            qp[jj][bi]   = 0.0f;
        }
    }

    const v4f* __restrict__ w0 = (const v4f*)(ISNet + (size_t)(j0 + 0) * NN);
    const v4f* __restrict__ w1 = (const v4f*)(ISNet + (size_t)(j0 + 1) * NN);
    const v4f* __restrict__ w2 = (const v4f*)(ISNet + (size_t)(j0 + 2) * NN);
    const v4f* __restrict__ w3 = (const v4f*)(ISNet + (size_t)(j0 + 3) * NN);
    const v4f* __restrict__ i0 = (const v4f*)(state + ((size_t)(b0 + 0) * 4 + 2) * NN);
    const v4f* __restrict__ i1 = (const v4f*)(state + ((size_t)(b0 + 1) * 4 + 2) * NN);

    v4f wA[JT], wB[JT], wC[JT], ia[2], ib[2];

// w loads: non-temporal (bypass L1 -- no reuse); I loads: normal (cached).
#define LW(BUF, IDX) do { const int _x = lane + (IDX) * 64; \
        BUF[0] = __builtin_nontemporal_load(&w0[_x]); \
        BUF[1] = __builtin_nontemporal_load(&w1[_x]); \
        BUF[2] = __builtin_nontemporal_load(&w2[_x]); \
        BUF[3] = __builtin_nontemporal_load(&w3[_x]); } while (0)
#define LI(BUF, IDX) do { const int _x = lane + (IDX) * 64; \
        BUF[0] = i0[_x]; BUF[1] = i1[_x]; } while (0)

    auto compute = [&](const v4f (&W)[JT], const v4f (&I)[2], bool odd) {
        #pragma unroll
        for (int jj = 0; jj < JT; ++jj) {
            const v2f w01 = {W[jj].x, W[jj].y};
            const v2f w23 = {W[jj].z, W[jj].w};
            #pragma unroll
            for (int bi = 0; bi < 2; ++bi) {
                const v4f& I4 = bi ? I[1] : I[0];
                const v2f c2  = {cf[jj][bi], cf[jj][bi]};
                const v2f i01 = {I4.x, I4.y};
                const v2f i23 = {I4.z, I4.w};
                const v2f z01 = (c2 * w01) * i01;              // v_pk_mul_f32
                const v2f z23 = (c2 * w23) * i23;              // v_pk_mul_f32
                const v2f q2  = __builtin_elementwise_fma(-z01, z23, z01 + z23);
                const float q4 = fmaf(-q2.x, q2.y, q2.x + q2.y);
                if (!odd) {
                    qp[jj][bi] = q4;                           // stash
                } else {
                    const float q8 = fmaf(-qp[jj][bi], q4, qp[jj][bi] + q4);
                    prod[jj][bi] = fma(-(double)q8, prod[jj][bi], prod[jj][bi]);
                }
            }
        }
    };

    // 16 stages; w triple-buffered (dist 3), I double-buffered (dist 2).
#define STEP(W, I, K) do { compute(W, I, (K) & 1); \
        if ((K) + 3 < 16) LW(W, (K) + 3); if ((K) + 2 < 16) LI(I, (K) + 2); } while (0)

    LW(wA, 0); LI(ia, 0); LW(wB, 1); LI(ib, 1); LW(wC, 2);
    STEP(wA, ia, 0);  STEP(wB, ib, 1);  STEP(wC, ia, 2);  STEP(wA, ib, 3);
    STEP(wB, ia, 4);  STEP(wC, ib, 5);  STEP(wA, ia, 6);  STEP(wB, ib, 7);
    STEP(wC, ia, 8);  STEP(wA, ib, 9);  STEP(wB, ia, 10); STEP(wC, ib, 11);
    STEP(wA, ia, 12); STEP(wB, ib, 13); STEP(wC, ia, 14); STEP(wA, ib, 15);
#undef STEP
#undef LW
#undef LI

    // 3 XOR-butterfly levels -> every lane holds its mod-8 residue partial.
    #pragma unroll
    for (int off = 32; off >= 8; off >>= 1) {
        #pragma unroll
        for (int jj = 0; jj < JT; ++jj) {
            #pragma unroll
            for (int bi = 0; bi < 2; ++bi)
                prod[jj][bi] *= __shfl_xor(prod[jj][bi], off, 64);
        }
    }

    // 8-lane group g reduces pair g = (jj<<1)|bi.
    const int g = lane >> 3;
    double v = prod[0][0];
    v = (g == 1) ? prod[0][1] : v; v = (g == 2) ? prod[1][0] : v;
    v = (g == 3) ? prod[1][1] : v; v = (g == 4) ? prod[2][0] : v;
    v = (g == 5) ? prod[2][1] : v; v = (g == 6) ? prod[3][0] : v;
    v = (g == 7) ? prod[3][1] : v;
    v *= __shfl_down(v, 4, 64);
    v *= __shfl_down(v, 2, 64);
    v *= __shfl_down(v, 1, 64);

    __shared__ double red[JT][BB];
    if ((lane & 7) == 0)               // pair g = (jj<<1)|bi
        red[g >> 1][b0 + (g & 1)] = v;
    __syncthreads();

    if (tid < JT * BB) {   // 32 threads: (jj, b)
        const int jj = tid >> 3, b = tid & 7;
        const int j  = j0 + jj;
        const double ps1 = 1.0 - red[jj][b];

        // expand_psMatrix in f64
        double pm[4][4];
        #pragma unroll
        for (int r = 0; r < 4; ++r) {
            double s = 0.0;
            #pragma unroll
            for (int q = 0; q < 4; ++q) {
                pm[r][q] = (double)psMatrix[r * 4 + q];
                s += pm[r][q];
            }
            pm[r][r] += (1.0 - s);
        }

        double st[4];
        #pragma unroll
        for (int r = 0; r < 4; ++r)
            st[r] = (double)state[(size_t)b * 4 * NN + r * NN + j];

        const double S = st[0];
        const double ps10[4] = {1.0 - ps1, ps1, 0.0, 0.0};

        double P[4];
        #pragma unroll
        for (int i = 0; i < 4; ++i) {
            double acc = S * ps10[i];
            #pragma unroll
            for (int r = 1; r < 4; ++r)
                acc += pm[r][i] * st[r];
            P[i] = acc;
        }

        double u = (double)U[j];
        #pragma unroll
        for (int i = 0; i < 4; ++i) {
            u -= P[i];
            const double s = (u < 0.0) ? 1.0 : 0.0;
            out[(size_t)b * 4 * NN + i * NN + j] = (float)s;
            u += s;
        }
    }
}

extern "C" void kernel_launch(void* const* d_in, const int* in_sizes, int n_in,
                              void* d_out, int out_size, void* d_ws, size_t ws_size,
                              hipStream_t stream) {
    const float* state    = (const float*)d_in[0];  // [8,4,4096]
    const float* ISNet    = (const float*)d_in[1];  // [4096,4096]
    const float* psMatrix = (const float*)d_in[2];  // [4,4]
    const float* U        = (const float*)d_in[3];  // [4096]
    float* out            = (float*)d_out;          // [8,4,4096]

    epi_kernel<<<NN / JT, 256, 0, stream>>>(state, ISNet, psMatrix, U, out);
}

// Round 19
// 28.284 us; speedup vs baseline: 1.1551x; 1.1551x over previous
//
#include <hip/hip_runtime.h>

// Problem constants (fixed by the reference file): B=8, N=4096.
#define NN 4096
#define BB 8
#define JT 4          // ISNet rows per block
#define BT 4          // batches per wave
#define KS 2          // in-block k-splits
#define KH (NN / KS)  // 2048 k per wave

typedef float v2f __attribute__((ext_vector_type(2)));
typedef float v4f __attribute__((ext_vector_type(4)));

// The untried matrix cell: R13's byte-lean tile (JT x BT = 16 pairs/lane,
// -33% bytes, compiled clean ~95 VGPR) + packed-f32 math via clang
// ext-vectors (v_pk_mul_f32 / v_pk_fma_f32, ~-40% VALU vs R13's
// struct-float2 helpers which lower to scalar) with the 4-FACTOR combine —
// no qp[] stash array, which is precisely what made R16 spill.
// Wave w -> (bg = w&1, ks = w>>1): rows j0..j0+3, batches bg*4..+3,
// k in [ks*KH, (ks+1)*KH). Single-buffered loads; in-block k-split combine
// via 512 B LDS + one barrier. R18 lesson: w loads stay NORMAL (L1-cached)
// -- nt-bypass cost 9 µs.

__global__ __launch_bounds__(256, 4) void epi_kernel(
    const float* __restrict__ state,    // [B,4,N]
    const float* __restrict__ ISNet,    // [N,N]
    const float* __restrict__ psMatrix, // [4,4]
    const float* __restrict__ U,        // [N]
    float* __restrict__ out)            // [B,4,N]
{
    const int j0   = blockIdx.x * JT;
    const int tid  = threadIdx.x;
    const int wave = tid >> 6;
    const int lane = tid & 63;
    const int bg   = wave & 1;
    const int ks   = wave >> 1;
    const int b0   = bg * BT;
    const int kb   = ks * KH;

    __shared__ double red[KS][JT][BB];   // 512 B

    const float p01 = psMatrix[1];       // psM[0,1] == psMatrix[0,1]

    float  cf[JT][BT];
    double prod[JT][BT];
    #pragma unroll
    for (int jj = 0; jj < JT; ++jj) {
        #pragma unroll
        for (int bi = 0; bi < BT; ++bi) {
            cf[jj][bi]   = state[(size_t)(b0 + bi) * 4 * NN + (j0 + jj)] * p01;
            prod[jj][bi] = 1.0;
        }
    }

    const v4f* __restrict__ w_0 = (const v4f*)(ISNet + (size_t)(j0 + 0) * NN + kb);
    const v4f* __restrict__ w_1 = (const v4f*)(ISNet + (size_t)(j0 + 1) * NN + kb);
    const v4f* __restrict__ w_2 = (const v4f*)(ISNet + (size_t)(j0 + 2) * NN + kb);
    const v4f* __restrict__ w_3 = (const v4f*)(ISNet + (size_t)(j0 + 3) * NN + kb);
    const v4f* __restrict__ i_0 = (const v4f*)(state + ((size_t)(b0 + 0) * 4 + 2) * NN + kb);
    const v4f* __restrict__ i_1 = (const v4f*)(state + ((size_t)(b0 + 1) * 4 + 2) * NN + kb);
    const v4f* __restrict__ i_2 = (const v4f*)(state + ((size_t)(b0 + 2) * 4 + 2) * NN + kb);
    const v4f* __restrict__ i_3 = (const v4f*)(state + ((size_t)(b0 + 3) * 4 + 2) * NN + kb);

#define COMP(JJ, BI, WV, IV)                                                   \
    do {                                                                       \
        const v2f c2  = {cf[JJ][BI], cf[JJ][BI]};                              \
        const v2f z01 = (c2 * (v2f){WV.x, WV.y}) * (v2f){IV.x, IV.y};          \
        const v2f z23 = (c2 * (v2f){WV.z, WV.w}) * (v2f){IV.z, IV.w};          \
        const v2f q2  = __builtin_elementwise_fma(-z01, z23, z01 + z23);       \
        const float q4 = fmaf(-q2.x, q2.y, q2.x + q2.y);                       \
        prod[JJ][BI] = fma(-(double)q4, prod[JJ][BI], prod[JJ][BI]);           \
    } while (0)

    #pragma unroll
    for (int it = 0; it < KH / 256; ++it) {   // 8 stages of 256 k
        const int x = lane + it * 64;
        const v4f wv0 = w_0[x], wv1 = w_1[x], wv2 = w_2[x], wv3 = w_3[x];
        const v4f iv0 = i_0[x], iv1 = i_1[x], iv2 = i_2[x], iv3 = i_3[x];

        COMP(0, 0, wv0, iv0); COMP(0, 1, wv0, iv1);
        COMP(0, 2, wv0, iv2); COMP(0, 3, wv0, iv3);
        COMP(1, 0, wv1, iv0); COMP(1, 1, wv1, iv1);
        COMP(1, 2, wv1, iv2); COMP(1, 3, wv1, iv3);
        COMP(2, 0, wv2, iv0); COMP(2, 1, wv2, iv1);
        COMP(2, 2, wv2, iv2); COMP(2, 3, wv2, iv3);
        COMP(3, 0, wv3, iv0); COMP(3, 1, wv3, iv1);
        COMP(3, 2, wv3, iv2); COMP(3, 3, wv3, iv3);
    }
#undef COMP

    // 3 XOR-butterfly levels: every lane holds the partial over its mod-8
    // residue class for all 16 (jj,bi) values.
    #pragma unroll
    for (int off = 32; off >= 8; off >>= 1) {
        #pragma unroll
        for (int jj = 0; jj < JT; ++jj) {
            #pragma unroll
            for (int bi = 0; bi < BT; ++bi)
                prod[jj][bi] *= __shfl_xor(prod[jj][bi], off, 64);
        }
    }

    // 8-lane group g reduces values (jj = g>>1, bi = (g&1)*2 + {0,1}).
    const int g = lane >> 3;
    double v0 = prod[0][0], v1 = prod[0][1];
    v0 = (g == 1) ? prod[0][2] : v0;  v1 = (g == 1) ? prod[0][3] : v1;
    v0 = (g == 2) ? prod[1][0] : v0;  v1 = (g == 2) ? prod[1][1] : v1;
    v0 = (g == 3) ? prod[1][2] : v0;  v1 = (g == 3) ? prod[1][3] : v1;
    v0 = (g == 4) ? prod[2][0] : v0;  v1 = (g == 4) ? prod[2][1] : v1;
    v0 = (g == 5) ? prod[2][2] : v0;  v1 = (g == 5) ? prod[2][3] : v1;
    v0 = (g == 6) ? prod[3][0] : v0;  v1 = (g == 6) ? prod[3][1] : v1;
    v0 = (g == 7) ? prod[3][2] : v0;  v1 = (g == 7) ? prod[3][3] : v1;
    v0 *= __shfl_down(v0, 4, 64);  v1 *= __shfl_down(v1, 4, 64);
    v0 *= __shfl_down(v0, 2, 64);  v1 *= __shfl_down(v1, 2, 64);
    v0 *= __shfl_down(v0, 1, 64);  v1 *= __shfl_down(v1, 1, 64);

    if ((lane & 7) == 0) {
        const int jj  = g >> 1;
        const int bi0 = (g & 1) * 2;
        red[ks][jj][b0 + bi0 + 0] = v0;
        red[ks][jj][b0 + bi0 + 1] = v1;
    }
    __syncthreads();

    if (tid < JT * BB) {   // 32 threads: (jj, b)
        const int jj = tid >> 3, b = tid & 7;
        const int j  = j0 + jj;
        const double tot = red[0][jj][b] * red[1][jj][b];
        const double ps1 = 1.0 - tot;

        // expand_psMatrix in f64
        double pm[4][4];
        #pragma unroll
        for (int r = 0; r < 4; ++r) {
            double s = 0.0;
            #pragma unroll
            for (int q = 0; q < 4; ++q) {
                pm[r][q] = (double)psMatrix[r * 4 + q];
                s += pm[r][q];
            }
            pm[r][r] += (1.0 - s);
        }

        double st[4];
        #pragma unroll
        for (int r = 0; r < 4; ++r)
            st[r] = (double)state[(size_t)b * 4 * NN + r * NN + j];

        const double S = st[0];
        const double ps10[4] = {1.0 - ps1, ps1, 0.0, 0.0};

        double P[4];
        #pragma unroll
        for (int i = 0; i < 4; ++i) {
            double acc = S * ps10[i];
            #pragma unroll
            for (int r = 1; r < 4; ++r)
                acc += pm[r][i] * st[r];
            P[i] = acc;
        }

        double u = (double)U[j];
        #pragma unroll
        for (int i = 0; i < 4; ++i) {
            u -= P[i];
            const double s = (u < 0.0) ? 1.0 : 0.0;
            out[(size_t)b * 4 * NN + i * NN + j] = (float)s;
            u += s;
        }
    }
}

extern "C" void kernel_launch(void* const* d_in, const int* in_sizes, int n_in,
                              void* d_out, int out_size, void* d_ws, size_t ws_size,
                              hipStream_t stream) {
    const float* state    = (const float*)d_in[0];  // [8,4,4096]
    const float* ISNet    = (const float*)d_in[1];  // [4096,4096]
    const float* psMatrix = (const float*)d_in[2];  // [4,4]
    const float* U        = (const float*)d_in[3];  // [4096]
    float* out            = (float*)d_out;          // [8,4,4096]

    epi_kernel<<<NN / JT, 256, 0, stream>>>(state, ISNet, psMatrix, U, out);
}

// Round 20
// 23.700 us; speedup vs baseline: 1.3785x; 1.1934x over previous
//
#include <hip/hip_runtime.h>

// Problem constants (fixed by the reference file): B=8, N=4096.
#define NN 4096
#define BB 8
#define JT 4   // ISNet rows (j) per block

typedef float v2f __attribute__((ext_vector_type(2)));

// FINAL: round-14 kernel restored verbatim (best measured: 23.8 µs; the
// session's 7 structural alternatives all landed 23.8-28.4 µs).
// Structure: 1024 blocks x 4 independent waves (no main-loop barriers);
// wave w owns batches {2w,2w+1} for rows j0..j0+3 over all k. w rows
// triple-buffered (dist 3), I rows double-buffered (dist 2), all float4.
// Math: z = (S*p01*w)*I in f32 packed pairs (v_pk_mul_f32/v_pk_fma_f32);
// 4 factors -> q4 via exact pairwise fmaf; q8 = q4_even ⊕ q4_odd in f32;
// one f64 fma per 8 factors keeps the running product near-exact
// (absmax 0 vs reference across all passing rounds).
// Reduction: 3 xor-butterfly levels (mod-8 residue partials) + per-group
// select + 3 down-levels; epilogue (4x4 mix + cumulative-threshold
// sampling) in f64 on 32 threads.

__global__ __launch_bounds__(256, 4) void epi_kernel(
    const float* __restrict__ state,    // [B,4,N]
    const float* __restrict__ ISNet,    // [N,N]
    const float* __restrict__ psMatrix, // [4,4]
    const float* __restrict__ U,        // [N]
    float* __restrict__ out)            // [B,4,N]
{
    const int j0   = blockIdx.x * JT;
    const int tid  = threadIdx.x;
    const int wave = tid >> 6;
    const int lane = tid & 63;
    const int b0   = wave * 2;          // this wave's two batches

    const float p01 = psMatrix[1];      // psM[0,1] == psMatrix[0,1]

    float  cf[JT][2];
    float  qp[JT][2];                   // pending q4 from the even stage
    double prod[JT][2];
    #pragma unroll
    for (int jj = 0; jj < JT; ++jj) {
        #pragma unroll
        for (int bi = 0; bi < 2; ++bi) {
            cf[jj][bi]   = state[(size_t)(b0 + bi) * 4 * NN + (j0 + jj)] * p01;
            prod[jj][bi] = 1.0;
            qp[jj][bi]   = 0.0f;
        }
    }

    const float4* __restrict__ w0 = (const float4*)(ISNet + (size_t)(j0 + 0) * NN);
    const float4* __restrict__ w1 = (const float4*)(ISNet + (size_t)(j0 + 1) * NN);
    const float4* __restrict__ w2 = (const float4*)(ISNet + (size_t)(j0 + 2) * NN);
    const float4* __restrict__ w3 = (const float4*)(ISNet + (size_t)(j0 + 3) * NN);
    const float4* __restrict__ i0 = (const float4*)(state + ((size_t)(b0 + 0) * 4 + 2) * NN);
    const float4* __restrict__ i1 = (const float4*)(state + ((size_t)(b0 + 1) * 4 + 2) * NN);

    float4 wA[JT], wB[JT], wC[JT], ia[2], ib[2];

#define LW(BUF, IDX) do { const int _x = lane + (IDX) * 64; \
        BUF[0] = w0[_x]; BUF[1] = w1[_x]; BUF[2] = w2[_x]; BUF[3] = w3[_x]; } while (0)
#define LI(BUF, IDX) do { const int _x = lane + (IDX) * 64; \
        BUF[0] = i0[_x]; BUF[1] = i1[_x]; } while (0)

    auto compute = [&](const float4 (&W)[JT], const float4 (&I)[2], bool odd) {
        #pragma unroll
        for (int jj = 0; jj < JT; ++jj) {
            const v2f w01 = {W[jj].x, W[jj].y};
            const v2f w23 = {W[jj].z, W[jj].w};
            #pragma unroll
            for (int bi = 0; bi < 2; ++bi) {
                const float4& I4 = bi ? I[1] : I[0];
                const v2f c2  = {cf[jj][bi], cf[jj][bi]};
                const v2f i01 = {I4.x, I4.y};
                const v2f i23 = {I4.z, I4.w};
                const v2f z01 = (c2 * w01) * i01;              // v_pk_mul_f32
                const v2f z23 = (c2 * w23) * i23;              // v_pk_mul_f32
                const v2f q2  = __builtin_elementwise_fma(-z01, z23, z01 + z23);
                const float q4 = fmaf(-q2.x, q2.y, q2.x + q2.y);
                if (!odd) {
                    qp[jj][bi] = q4;                           // stash
                } else {
                    const float q8 = fmaf(-qp[jj][bi], q4, qp[jj][bi] + q4);
                    prod[jj][bi] = fma(-(double)q8, prod[jj][bi], prod[jj][bi]);
                }
            }
        }
    };

    // 16 stages; w triple-buffered (dist 3), I double-buffered (dist 2).
#define STEP(W, I, K) do { compute(W, I, (K) & 1); \
        if ((K) + 3 < 16) LW(W, (K) + 3); if ((K) + 2 < 16) LI(I, (K) + 2); } while (0)

    LW(wA, 0); LI(ia, 0); LW(wB, 1); LI(ib, 1); LW(wC, 2);
    STEP(wA, ia, 0);  STEP(wB, ib, 1);  STEP(wC, ia, 2);  STEP(wA, ib, 3);
    STEP(wB, ia, 4);  STEP(wC, ib, 5);  STEP(wA, ia, 6);  STEP(wB, ib, 7);
    STEP(wC, ia, 8);  STEP(wA, ib, 9);  STEP(wB, ia, 10); STEP(wC, ib, 11);
    STEP(wA, ia, 12); STEP(wB, ib, 13); STEP(wC, ia, 14); STEP(wA, ib, 15);
#undef STEP
#undef LW
#undef LI

    // 3 XOR-butterfly levels -> every lane holds its mod-8 residue partial.
    #pragma unroll
    for (int off = 32; off >= 8; off >>= 1) {
        #pragma unroll
        for (int jj = 0; jj < JT; ++jj) {
            #pragma unroll
            for (int bi = 0; bi < 2; ++bi)
                prod[jj][bi] *= __shfl_xor(prod[jj][bi], off, 64);
        }
    }

    // 8-lane group g reduces pair g = (jj<<1)|bi.
    const int g = lane >> 3;
    double v = prod[0][0];
    v = (g == 1) ? prod[0][1] : v; v = (g == 2) ? prod[1][0] : v;
    v = (g == 3) ? prod[1][1] : v; v = (g == 4) ? prod[2][0] : v;
    v = (g == 5) ? prod[2][1] : v; v = (g == 6) ? prod[3][0] : v;
    v = (g == 7) ? prod[3][1] : v;
    v *= __shfl_down(v, 4, 64);
    v *= __shfl_down(v, 2, 64);
    v *= __shfl_down(v, 1, 64);

    __shared__ double red[JT][BB];
    if ((lane & 7) == 0)               // pair g = (jj<<1)|bi
        red[g >> 1][b0 + (g & 1)] = v;
    __syncthreads();

    if (tid < JT * BB) {   // 32 threads: (jj, b)
        const int jj = tid >> 3, b = tid & 7;
        const int j  = j0 + jj;
        const double ps1 = 1.0 - red[jj][b];

        // expand_psMatrix in f64
        double pm[4][4];
        #pragma unroll
        for (int r = 0; r < 4; ++r) {
            double s = 0.0;
            #pragma unroll
            for (int q = 0; q < 4; ++q) {
                pm[r][q] = (double)psMatrix[r * 4 + q];
                s += pm[r][q];
            }
            pm[r][r] += (1.0 - s);
        }

        double st[4];
        #pragma unroll
        for (int r = 0; r < 4; ++r)
            st[r] = (double)state[(size_t)b * 4 * NN + r * NN + j];

        const double S = st[0];
        const double ps10[4] = {1.0 - ps1, ps1, 0.0, 0.0};

        double P[4];
        #pragma unroll
        for (int i = 0; i < 4; ++i) {
            double acc = S * ps10[i];
            #pragma unroll
            for (int r = 1; r < 4; ++r)
                acc += pm[r][i] * st[r];
            P[i] = acc;
        }

        double u = (double)U[j];
        #pragma unroll
        for (int i = 0; i < 4; ++i) {
            u -= P[i];
            const double s = (u < 0.0) ? 1.0 : 0.0;
            out[(size_t)b * 4 * NN + i * NN + j] = (float)s;
            u += s;
        }
    }
}

extern "C" void kernel_launch(void* const* d_in, const int* in_sizes, int n_in,
                              void* d_out, int out_size, void* d_ws, size_t ws_size,
                              hipStream_t stream) {
    const float* state    = (const float*)d_in[0];  // [8,4,4096]
    const float* ISNet    = (const float*)d_in[1];  // [4096,4096]
    const float* psMatrix = (const float*)d_in[2];  // [4,4]
    const float* U        = (const float*)d_in[3];  // [4096]
    float* out            = (float*)d_out;          // [8,4,4096]

    epi_kernel<<<NN / JT, 256, 0, stream>>>(state, ISNet, psMatrix, U, out);
}